// Round 23
// baseline (416.117 us; speedup 1.0000x reference)
//
#include <hip/hip_runtime.h>
#include <float.h>

#define NV 4096
#define OSTRIDE 451
#define NT 256
#define PK1OFF 6291456                 // float4[32768]  (131072 floats)
#define PK2OFF (6291456 + 131072)      // float4[16384]  (65536 floats)
#define PK3OFF (6291456 + 196608)      // float4[8192]   (32768 floats)
#define MARGIN 1e-3f
typedef unsigned long long u64;

// Wave-uniform top-8 list held as f32 BIT PATTERNS (u32) + idx, kept in
// SGPRs: d2 >= 0 so u32 compare == f32 compare. All inserts are uniform
// u32 ternaries -> SALU (s_cmp/s_cselect), freeing the VALU pipe.
struct Top8 {
    unsigned d0,d1,d2,d3,d4,d5,d6,d7;   // ascending
    int      i0,i1,i2,i3,i4,i5,i6,i7;
};

__device__ __forceinline__ void top8_init(Top8& t) {
    t.d0=t.d1=t.d2=t.d3=t.d4=t.d5=t.d6=t.d7=0x7F7FFFFFu;  // FLT_MAX bits
    t.i0=t.i1=t.i2=t.i3=t.i4=t.i5=t.i6=t.i7=0x7fffffff;
}

// sorted ascending insert (caller guarantees cd < t.d7); STRICT < placement:
// equal-key candidates go after existing entries, so ascending-idx processing
// reproduces top_k's stable tie semantics exactly within a contiguous part.
__device__ __forceinline__ void ins8s(Top8& t, unsigned cd, int cm) {
    bool b0 = cd < t.d0, b1 = cd < t.d1, b2 = cd < t.d2, b3 = cd < t.d3;
    bool b4 = cd < t.d4, b5 = cd < t.d5, b6 = cd < t.d6;
    t.d7 = b6 ? t.d6 : cd;                 t.i7 = b6 ? t.i6 : cm;
    t.d6 = b5 ? t.d5 : (b6 ? cd : t.d6);   t.i6 = b5 ? t.i5 : (b6 ? cm : t.i6);
    t.d5 = b4 ? t.d4 : (b5 ? cd : t.d5);   t.i5 = b4 ? t.i4 : (b5 ? cm : t.i5);
    t.d4 = b3 ? t.d3 : (b4 ? cd : t.d4);   t.i4 = b3 ? t.i3 : (b4 ? cm : t.i4);
    t.d3 = b2 ? t.d2 : (b3 ? cd : t.d3);   t.i3 = b2 ? t.i2 : (b3 ? cm : t.i3);
    t.d2 = b1 ? t.d1 : (b2 ? cd : t.d2);   t.i2 = b1 ? t.i1 : (b2 ? cm : t.i2);
    t.d1 = b0 ? t.d0 : (b1 ? cd : t.d1);   t.i1 = b0 ? t.i0 : (b1 ? cm : t.i1);
    t.d0 = b0 ? cd : t.d0;                 t.i0 = b0 ? cm : t.i0;
}

// lexicographic (d2, idx) insert — used ONLY for the s1 part-merge. Since
// all part0 idx < part1 idx, folding part1's sorted list into part0's with
// lex compare yields the exact global top-8 with top_k tie semantics.
__device__ __forceinline__ void ins8lex(Top8& t, unsigned cd, int cm) {
    bool b0 = (cd < t.d0) || (cd == t.d0 && cm < t.i0);
    bool b1 = (cd < t.d1) || (cd == t.d1 && cm < t.i1);
    bool b2 = (cd < t.d2) || (cd == t.d2 && cm < t.i2);
    bool b3 = (cd < t.d3) || (cd == t.d3 && cm < t.i3);
    bool b4 = (cd < t.d4) || (cd == t.d4 && cm < t.i4);
    bool b5 = (cd < t.d5) || (cd == t.d5 && cm < t.i5);
    bool b6 = (cd < t.d6) || (cd == t.d6 && cm < t.i6);
    t.d7 = b6 ? t.d6 : cd;                 t.i7 = b6 ? t.i6 : cm;
    t.d6 = b5 ? t.d5 : (b6 ? cd : t.d6);   t.i6 = b5 ? t.i5 : (b6 ? cm : t.i6);
    t.d5 = b4 ? t.d4 : (b5 ? cd : t.d5);   t.i5 = b4 ? t.i4 : (b5 ? cm : t.i5);
    t.d4 = b3 ? t.d3 : (b4 ? cd : t.d4);   t.i4 = b3 ? t.i3 : (b4 ? cm : t.i4);
    t.d3 = b2 ? t.d2 : (b3 ? cd : t.d3);   t.i3 = b2 ? t.i2 : (b3 ? cm : t.i3);
    t.d2 = b1 ? t.d1 : (b2 ? cd : t.d2);   t.i2 = b1 ? t.i1 : (b2 ? cm : t.i2);
    t.d1 = b0 ? t.d0 : (b1 ? cd : t.d1);   t.i1 = b0 ? t.i0 : (b1 ? cm : t.i1);
    t.d0 = b0 ? cd : t.d0;                 t.i0 = b0 ? cm : t.i0;
}

// wave-uniform event loop; ascending lane = ascending idx within the mask.
// seedlim skips this part's seed points. Refilter after each insert.
// Only VALU per event: 1 readlane + 1 refilter v_cmp; rest is SALU.
__device__ __forceinline__ void handle_p(u64 mask, float dj, int ibase,
                                         int seedlim, Top8& t, float& Tf) {
    while (mask) {
        int l = __builtin_ctzll(mask);
        mask &= mask - 1;
        int cm = ibase + l;
        if (cm < seedlim) continue;
        unsigned cd = (unsigned)__builtin_amdgcn_readlane(__float_as_uint(dj), l);
        if (cd < t.d7) {
            ins8s(t, cd, cm);
            Tf = __uint_as_float(t.d7);
            mask &= __ballot(dj < Tf);             // refilter vs tightened T
        }
    }
}

// weight: reference recomputes dist2 from vec = nbr - vert, numpy op order
// (round products, sequential add, no fma), w = 1/(1+dist2)
template<int M>
__device__ __forceinline__ float wcalc(const float* __restrict__ pc, int m,
                                       float vx, float vy, float vz) {
    float qx = pc[m], qy = pc[M+m], qz = pc[2*M+m];
    float dx = __fsub_rn(qx, vx), dy = __fsub_rn(qy, vy), dz = __fsub_rn(qz, vz);
    float dist2 = __fadd_rn(__fadd_rn(__fmul_rn(dx,dx), __fmul_rn(dy,dy)),
                            __fmul_rn(dz,dz));
    return __fdiv_rn(1.0f, __fadd_rn(1.0f, dist2));
}

// The R16-proven PK scan body, parameterized by runtime [base, base+LEN).
// Everything local (no register arrays cross function boundaries; only the
// proven leaf handle_p takes Top8&) — guards against the R19/R21 scratch
// failure. Surrogate gate (3 fma/pair) vs conservative T-(|v|^2-MARGIN);
// exact direct-form recheck (strict <); in-order SALU handler.
#define SCAN_PK_BODY(PKP, BASE, LEN)                                          \
    {                                                                         \
        float c0[2], c1[2], c2[2], v2m[2], Tg[2];                             \
        _Pragma("unroll")                                                     \
        for (int u = 0; u < 2; ++u) {                                         \
            c0[u] = __fmul_rn(-2.0f, vx[u]);                                  \
            c1[u] = __fmul_rn(-2.0f, vy[u]);                                  \
            c2[u] = __fmul_rn(-2.0f, vz[u]);                                  \
            float v2 = __fadd_rn(__fadd_rn(__fmul_rn(vx[u],vx[u]),            \
                       __fmul_rn(vy[u],vy[u])), __fmul_rn(vz[u],vz[u]));      \
            v2m[u] = __fsub_rn(v2, MARGIN);                                   \
            Tg[u]  = __fsub_rn(T[u], v2m[u]);                                 \
        }                                                                     \
        float4 cp[4];                                                         \
        _Pragma("unroll")                                                     \
        for (int j = 0; j < 4; ++j) cp[j] = (PKP)[(BASE) + 64*j + lane];      \
        for (int ob = 0; ob < (LEN); ob += 256) {                             \
            int nb = (ob + 256 < (LEN)) ? ob + 256 : 0;                       \
            float4 np[4];                                                     \
            _Pragma("unroll")                                                 \
            for (int j = 0; j < 4; ++j) np[j] = (PKP)[(BASE) + nb + 64*j + lane]; \
            float s0[4], s1[4];                                               \
            _Pragma("unroll")                                                 \
            for (int j = 0; j < 4; ++j) {                                     \
                s0[j] = __fmaf_rn(cp[j].x, c0[0], __fmaf_rn(cp[j].y, c1[0],   \
                        __fmaf_rn(cp[j].z, c2[0], cp[j].w)));                 \
                s1[j] = __fmaf_rn(cp[j].x, c0[1], __fmaf_rn(cp[j].y, c1[1],   \
                        __fmaf_rn(cp[j].z, c2[1], cp[j].w)));                 \
            }                                                                 \
            u64 g0[4], g1[4]; u64 any = 0;                                    \
            _Pragma("unroll")                                                 \
            for (int j = 0; j < 4; ++j) {                                     \
                g0[j] = __ballot(s0[j] < Tg[0]);                              \
                g1[j] = __ballot(s1[j] < Tg[1]);                              \
                any |= g0[j] | g1[j];                                         \
            }                                                                 \
            if (any) {                                                        \
                _Pragma("unroll")                                             \
                for (int j = 0; j < 4; ++j) {                                 \
                    if (g0[j]) {                                              \
                        float dx = __fsub_rn(cp[j].x, vx[0]);                 \
                        float dy = __fsub_rn(cp[j].y, vy[0]);                 \
                        float dz = __fsub_rn(cp[j].z, vz[0]);                 \
                        float d2x = __fmaf_rn(dz,dz,__fmaf_rn(dy,dy,__fmul_rn(dx,dx))); \
                        u64 em = __ballot(d2x < T[0]);                        \
                        if (em) {                                             \
                            handle_p(em, d2x, (BASE) + ob + 64*j, (BASE) + 8, t0, T[0]); \
                            Tg[0] = __fsub_rn(T[0], v2m[0]);                  \
                        }                                                     \
                    }                                                         \
                }                                                             \
                _Pragma("unroll")                                             \
                for (int j = 0; j < 4; ++j) {                                 \
                    if (g1[j]) {                                              \
                        float dx = __fsub_rn(cp[j].x, vx[1]);                 \
                        float dy = __fsub_rn(cp[j].y, vy[1]);                 \
                        float dz = __fsub_rn(cp[j].z, vz[1]);                 \
                        float d2x = __fmaf_rn(dz,dz,__fmaf_rn(dy,dy,__fmul_rn(dx,dx))); \
                        u64 em = __ballot(d2x < T[1]);                        \
                        if (em) {                                             \
                            handle_p(em, d2x, (BASE) + ob + 64*j, (BASE) + 8, t1, T[1]); \
                            Tg[1] = __fsub_rn(T[1], v2m[1]);                  \
                        }                                                     \
                    }                                                         \
                }                                                             \
            }                                                                 \
            _Pragma("unroll")                                                 \
            for (int j = 0; j < 4; ++j) cp[j] = np[j];                        \
        }                                                                     \
    }

// seeds for a part: points BASE..BASE+7 in ascending idx order (exact)
#define SEED2(PCP, MM, BASE)                                                  \
    _Pragma("unroll")                                                         \
    for (int q = 0; q < 8; ++q) {                                             \
        float sx = (PCP)[(BASE)+q], sy = (PCP)[(MM)+(BASE)+q], sz = (PCP)[2*(MM)+(BASE)+q]; \
        {                                                                     \
            float dx=__fsub_rn(sx,vx[0]), dy=__fsub_rn(sy,vy[0]), dz=__fsub_rn(sz,vz[0]); \
            float d = __fmaf_rn(dz,dz,__fmaf_rn(dy,dy,__fmul_rn(dx,dx)));     \
            unsigned cd = (unsigned)__builtin_amdgcn_readfirstlane(__float_as_uint(d)); \
            if (cd < t0.d7) ins8s(t0, cd, (BASE)+q);                          \
        }                                                                     \
        {                                                                     \
            float dx=__fsub_rn(sx,vx[1]), dy=__fsub_rn(sy,vy[1]), dz=__fsub_rn(sz,vz[1]); \
            float d = __fmaf_rn(dz,dz,__fmaf_rn(dy,dy,__fmul_rn(dx,dx)));     \
            unsigned cd = (unsigned)__builtin_amdgcn_readfirstlane(__float_as_uint(d)); \
            if (cd < t1.d7) ins8s(t1, cd, (BASE)+q);                          \
        }                                                                     \
    }

// weights + feature mean for 2 verts (numpy op order; featT gather)
#define EMIT2(PCP, MM, DFV, COFFV)                                            \
    {                                                                         \
        int m8[2][8];                                                         \
        m8[0][0]=t0.i0; m8[0][1]=t0.i1; m8[0][2]=t0.i2; m8[0][3]=t0.i3;       \
        m8[0][4]=t0.i4; m8[0][5]=t0.i5; m8[0][6]=t0.i6; m8[0][7]=t0.i7;       \
        m8[1][0]=t1.i0; m8[1][1]=t1.i1; m8[1][2]=t1.i2; m8[1][3]=t1.i3;       \
        m8[1][4]=t1.i4; m8[1][5]=t1.i5; m8[1][6]=t1.i6; m8[1][7]=t1.i7;       \
        _Pragma("unroll")                                                     \
        for (int u = 0; u < 2; ++u) {                                         \
            float w8[8];                                                      \
            _Pragma("unroll")                                                 \
            for (int k = 0; k < 8; ++k)                                       \
                w8[k] = wcalc<(MM)>((PCP), m8[u][k], vx[u], vy[u], vz[u]);    \
            const int n = vbase + u;                                          \
            for (int f = lane; f < (DFV); f += 64) {                          \
                float e[8];                                                   \
                _Pragma("unroll")                                             \
                for (int k = 0; k < 8; ++k)                                   \
                    e[k] = __fmul_rn(w8[k], featT[m8[u][k]*(DFV) + f]);       \
                float s = __fadd_rn(__fadd_rn(__fadd_rn(e[0],e[1]), __fadd_rn(e[2],e[3])), \
                                    __fadd_rn(__fadd_rn(e[4],e[5]), __fadd_rn(e[6],e[7]))); \
                out[n*OSTRIDE + (COFFV) + f] = __fmul_rn(0.125f, s);          \
            }                                                                 \
        }                                                                     \
    }

// s2/s3 full-pair scan (R16 numerics): self-contained, all locals.
template<int M, int DF, int COFF>
__device__ __forceinline__ void stage_full(
    const float* __restrict__ verts, const float* __restrict__ pc,
    const float* __restrict__ featT, const float4* __restrict__ pk,
    float* __restrict__ out, int vbase, int lane)
{
    float vx[2], vy[2], vz[2];
#pragma unroll
    for (int u = 0; u < 2; ++u) {
        vx[u] = verts[(vbase+u)*3+0];
        vy[u] = verts[(vbase+u)*3+1];
        vz[u] = verts[(vbase+u)*3+2];
    }
    Top8 t0, t1; top8_init(t0); top8_init(t1);
    SEED2(pc, M, 0)
    float T[2];
    T[0] = __uint_as_float(t0.d7);
    T[1] = __uint_as_float(t1.d7);
    SCAN_PK_BODY(pk, 0, M)
    EMIT2(pc, M, DF, COFF)
}

// Equal-duration grid: every scan wave = 16384 points = 64 batches.
//   b < 1024 : s1 block — 4 waves = 2 pairs x 2 parts; LDS merge; part0 emits
//   b < 1536 : s2 block — 4 waves x 1 pair
//   b < 1792 : s3 block — 4 waves x 2 sequential pairs
//   b = 1792 : coord copy
// 1792 = exactly 7 blocks/CU -> one residency round, zero drain tail.
__global__ __launch_bounds__(NT, 7)
void gp_eq(const float* __restrict__ verts,
           const float* __restrict__ pc1, const float* __restrict__ pc2,
           const float* __restrict__ pc3,
           const float* __restrict__ ws, float* __restrict__ out)
{
    __shared__ unsigned smd[2][16];   // [pair-slot][vert*8+k]
    __shared__ int      smi[2][16];
    const int b = blockIdx.x;
    if (b >= 1792) {
        for (int i = threadIdx.x; i < NV*3; i += NT)
            out[(i/3)*OSTRIDE + (i % 3)] = verts[i];
        return;
    }
    const int lane = threadIdx.x & 63;
    const int wv   = threadIdx.x >> 6;
    const float* featT1 = ws;
    const float* featT2 = ws + 2097152;
    const float* featT3 = ws + 4194304;
    const float4* pk1 = (const float4*)(ws + PK1OFF);
    const float4* pk2 = (const float4*)(ws + PK2OFF);
    const float4* pk3 = (const float4*)(ws + PK3OFF);

    if (b < 1024) {
        // s1: slot = wv>>1 (pair within block), part = wv&1
        const int slot  = wv >> 1;
        const int part  = wv & 1;
        const int vbase = (b*2 + slot)*2;
        const int base  = part * 16384;
        const float* featT = featT1;
        float vx[2], vy[2], vz[2];
#pragma unroll
        for (int u = 0; u < 2; ++u) {
            vx[u] = verts[(vbase+u)*3+0];
            vy[u] = verts[(vbase+u)*3+1];
            vz[u] = verts[(vbase+u)*3+2];
        }
        Top8 t0, t1; top8_init(t0); top8_init(t1);
        SEED2(pc1, 32768, base)
        float T[2];
        T[0] = __uint_as_float(t0.d7);
        T[1] = __uint_as_float(t1.d7);
        SCAN_PK_BODY(pk1, base, 16384)
        // publish part1's sorted lists; part0 folds them in (lex compare)
        if (part == 1 && lane == 0) {
            smd[slot][0]=t0.d0; smd[slot][1]=t0.d1; smd[slot][2]=t0.d2; smd[slot][3]=t0.d3;
            smd[slot][4]=t0.d4; smd[slot][5]=t0.d5; smd[slot][6]=t0.d6; smd[slot][7]=t0.d7;
            smi[slot][0]=t0.i0; smi[slot][1]=t0.i1; smi[slot][2]=t0.i2; smi[slot][3]=t0.i3;
            smi[slot][4]=t0.i4; smi[slot][5]=t0.i5; smi[slot][6]=t0.i6; smi[slot][7]=t0.i7;
            smd[slot][8]=t1.d0; smd[slot][9]=t1.d1; smd[slot][10]=t1.d2; smd[slot][11]=t1.d3;
            smd[slot][12]=t1.d4; smd[slot][13]=t1.d5; smd[slot][14]=t1.d6; smd[slot][15]=t1.d7;
            smi[slot][8]=t1.i0; smi[slot][9]=t1.i1; smi[slot][10]=t1.i2; smi[slot][11]=t1.i3;
            smi[slot][12]=t1.i4; smi[slot][13]=t1.i5; smi[slot][14]=t1.i6; smi[slot][15]=t1.i7;
        }
        __syncthreads();
        if (part == 0) {
#pragma unroll 1
            for (int s = 0; s < 8; ++s) {
                unsigned cd = __builtin_amdgcn_readfirstlane(smd[slot][s]);
                int      cm = __builtin_amdgcn_readfirstlane(smi[slot][s]);
                if (!((cd < t0.d7) || (cd == t0.d7 && cm < t0.i7))) break;
                ins8lex(t0, cd, cm);
            }
#pragma unroll 1
            for (int s = 0; s < 8; ++s) {
                unsigned cd = __builtin_amdgcn_readfirstlane(smd[slot][8+s]);
                int      cm = __builtin_amdgcn_readfirstlane(smi[slot][8+s]);
                if (!((cd < t1.d7) || (cd == t1.d7 && cm < t1.i7))) break;
                ins8lex(t1, cd, cm);
            }
            EMIT2(pc1, 32768, 64, 3)
        }
    } else if (b < 1536) {
        const int vbase = ((b-1024)*4 + wv)*2;
        stage_full<16384, 128, 67>(verts, pc2, featT2, pk2, out, vbase, lane);
    } else {
        const int q = (b-1536)*4 + wv;          // [0,1024)
        stage_full<8192, 256, 195>(verts, pc3, featT3, pk3, out, (q*2+0)*2, lane);
        stage_full<8192, 256, 195>(verts, pc3, featT3, pk3, out, (q*2+1)*2, lane);
    }
}

// LDS-tiled transpose (blocks 0..1535): feat [Df,M] -> featT [M,Df], both
// sides coalesced. Blocks 1536..1759: fill packed float4 (x,y,z,|p|^2)
// arrays (bit-copies of pc values -> scan numerics unchanged).
__global__ __launch_bounds__(256)
void tr_kernel(const float* __restrict__ f1, const float* __restrict__ f2,
               const float* __restrict__ f3,
               const float* __restrict__ pc1, const float* __restrict__ pc2,
               const float* __restrict__ pc3, float* __restrict__ ws)
{
    int b = blockIdx.x;
    if (b >= 1536) {
        int g = (b - 1536)*256 + threadIdx.x;       // 0..57343
        float x, y, z; float4* dst;
        if (g < 32768)      { x=pc1[g];      y=pc1[32768+g];  z=pc1[65536+g];  dst=(float4*)(ws+PK1OFF)+g; }
        else if (g < 49152) { int m=g-32768; x=pc2[m]; y=pc2[16384+m]; z=pc2[32768+m]; dst=(float4*)(ws+PK2OFF)+m; }
        else                { int m=g-49152; x=pc3[m]; y=pc3[8192+m];  z=pc3[16384+m]; dst=(float4*)(ws+PK3OFF)+m; }
        float pn = __fmaf_rn(z,z,__fmaf_rn(y,y,__fmul_rn(x,x)));
        *dst = make_float4(x, y, z, pn);
        return;
    }
    __shared__ float s[64][65];
    const float* src; float* dst; int M, DF, tm, tf;
    if (b < 512)       { src = f1; dst = ws;           M = 32768; DF = 64;  tm = b & 511;        tf = b >> 9; }
    else if (b < 1024) { src = f2; dst = ws + 2097152; M = 16384; DF = 128; tm = (b-512) & 255;  tf = (b-512) >> 8; }
    else               { src = f3; dst = ws + 4194304; M = 8192;  DF = 256; tm = (b-1024) & 127; tf = (b-1024) >> 7; }
    const int mb = tm*64, fb = tf*64;
    const int tid = threadIdx.x;
    const int a0 = tid & 63, a1 = tid >> 6;
#pragma unroll
    for (int i = 0; i < 16; ++i) {
        int ff = a1 + i*4;
        s[ff][a0] = src[(fb+ff)*M + mb + a0];
    }
    __syncthreads();
#pragma unroll
    for (int i = 0; i < 16; ++i) {
        int mm2 = a1 + i*4;
        dst[(mb+mm2)*DF + fb + a0] = s[a0][mm2];
    }
}

extern "C" void kernel_launch(void* const* d_in, const int* in_sizes, int n_in,
                              void* d_out, int out_size, void* d_ws, size_t ws_size,
                              hipStream_t stream) {
    const float* verts = (const float*)d_in[0];
    // d_in[1] = pc0_coords: unused (reference discards stage 0)
    const float* pc1 = (const float*)d_in[2];
    const float* f1  = (const float*)d_in[3];
    const float* pc2 = (const float*)d_in[4];
    const float* f2  = (const float*)d_in[5];
    const float* pc3 = (const float*)d_in[6];
    const float* f3  = (const float*)d_in[7];
    float* out = (float*)d_out;
    float* ws  = (float*)d_ws;

    // requires PK workspace (present in all observed runs)
    tr_kernel<<<1760, 256, 0, stream>>>(f1, f2, f3, pc1, pc2, pc3, ws);
    gp_eq<<<1793, NT, 0, stream>>>(verts, pc1, pc2, pc3, ws, out);
}

// Round 24
// 114.715 us; speedup vs baseline: 3.6274x; 3.6274x over previous
//
#include <hip/hip_runtime.h>
#include <float.h>

#define NV 4096
#define OSTRIDE 451
#define NT 256
#define PK1OFF 6291456                 // float4[32768]  (131072 floats)
#define PK2OFF (6291456 + 131072)      // float4[16384]  (65536 floats)
#define PK3OFF (6291456 + 196608)      // float4[8192]   (32768 floats)
#define MARGIN 1e-3f
typedef unsigned long long u64;

// Wave-uniform top-8 list held as f32 BIT PATTERNS (u32) + idx, kept in
// SGPRs: d2 >= 0 so u32 compare == f32 compare. All inserts are uniform
// u32 ternaries -> SALU (s_cmp/s_cselect), freeing the VALU pipe.
struct Top8 {
    unsigned d0,d1,d2,d3,d4,d5,d6,d7;   // ascending
    int      i0,i1,i2,i3,i4,i5,i6,i7;
};

__device__ __forceinline__ void top8_init(Top8& t) {
    t.d0=t.d1=t.d2=t.d3=t.d4=t.d5=t.d6=t.d7=0x7F7FFFFFu;  // FLT_MAX bits
    t.i0=t.i1=t.i2=t.i3=t.i4=t.i5=t.i6=t.i7=0x7fffffff;
}

// sorted ascending insert (caller guarantees cd < t.d7); STRICT < placement:
// equal-key candidates go after existing entries, so ascending-idx processing
// reproduces top_k's stable tie semantics exactly. (PARTS=1: no merges.)
__device__ __forceinline__ void ins8s(Top8& t, unsigned cd, int cm) {
    bool b0 = cd < t.d0, b1 = cd < t.d1, b2 = cd < t.d2, b3 = cd < t.d3;
    bool b4 = cd < t.d4, b5 = cd < t.d5, b6 = cd < t.d6;
    t.d7 = b6 ? t.d6 : cd;                 t.i7 = b6 ? t.i6 : cm;
    t.d6 = b5 ? t.d5 : (b6 ? cd : t.d6);   t.i6 = b5 ? t.i5 : (b6 ? cm : t.i6);
    t.d5 = b4 ? t.d4 : (b5 ? cd : t.d5);   t.i5 = b4 ? t.i4 : (b5 ? cm : t.i5);
    t.d4 = b3 ? t.d3 : (b4 ? cd : t.d4);   t.i4 = b3 ? t.i3 : (b4 ? cm : t.i4);
    t.d3 = b2 ? t.d2 : (b3 ? cd : t.d3);   t.i3 = b2 ? t.i2 : (b3 ? cm : t.i3);
    t.d2 = b1 ? t.d1 : (b2 ? cd : t.d2);   t.i2 = b1 ? t.i1 : (b2 ? cm : t.i2);
    t.d1 = b0 ? t.d0 : (b1 ? cd : t.d1);   t.i1 = b0 ? t.i0 : (b1 ? cm : t.i1);
    t.d0 = b0 ? cd : t.d0;                 t.i0 = b0 ? cm : t.i0;
}

// wave-uniform event loop; ctz order = ascending lane = ascending idx within
// this mask (idx = ibase + lane). Refilter after each insert prunes storms.
// Only VALU per event: 1 readlane + 1 refilter v_cmp; rest is SALU.
__device__ __forceinline__ void handle_s(u64 mask, float dj, int ibase,
                                         Top8& t, float& Tf) {
    while (mask) {
        int l = __builtin_ctzll(mask);
        mask &= mask - 1;
        int cm = ibase + l;
        if (cm < 8) continue;                      // seed points already in list
        unsigned cd = (unsigned)__builtin_amdgcn_readlane(__float_as_uint(dj), l);
        if (cd < t.d7) {
            ins8s(t, cd, cm);
            Tf = __uint_as_float(t.d7);
            mask &= __ballot(dj < Tf);             // refilter vs tightened T
        }
    }
}

// weight: reference recomputes dist2 from vec = nbr - vert, numpy op order
// (round products, sequential add, no fma), w = 1/(1+dist2)
template<int M>
__device__ __forceinline__ float wcalc(const float* __restrict__ pc, int m,
                                       float vx, float vy, float vz) {
    float qx = pc[m], qy = pc[M+m], qz = pc[2*M+m];
    float dx = __fsub_rn(qx, vx), dy = __fsub_rn(qy, vy), dz = __fsub_rn(qz, vz);
    float dist2 = __fadd_rn(__fadd_rn(__fmul_rn(dx,dx), __fmul_rn(dy,dy)),
                            __fmul_rn(dz,dz));
    return __fdiv_rn(1.0f, __fadd_rn(1.0f, dist2));
}

// One wave owns 2 vertices, full scan of one stage (PARTS=1: minimal events,
// no merges, no LDS, no barriers). 256-pt batches, lane-strided (lane l ->
// idx ob+64j+l, j-major processing = globally idx-ascending -> exact ties).
// PK path: one float4 (x,y,z,|p|^2) load per lane per j -> 4 VMEM/batch
// (vs 16 scalar); gate with monotone surrogate s = pn - 2 p.v (3 fma/pair)
// against conservative threshold T - (|v|^2 - MARGIN); on hit, recompute the
// exact direct-form d2 (bit-identical values: pack is a bit-copy of pc) and
// re-ballot against T before the SALU handler -> selection identical.
template<int M, int DF, int COFF, bool TR, bool PK>
__device__ __forceinline__ void stage2v(
    const float* __restrict__ verts,
    const float* __restrict__ pc,      // [3*M]
    const float* __restrict__ feat,    // [DF*M] (fallback gather)
    const float* __restrict__ featT,   // [M*DF] (transposed gather)
    const float4* __restrict__ pk,     // [M] packed (x,y,z,|p|^2) (PK only)
    float* __restrict__ out,
    int vbase, int lane)
{
    float vx[2], vy[2], vz[2];
#pragma unroll
    for (int u = 0; u < 2; ++u) {
        vx[u] = verts[(vbase+u)*3+0];
        vy[u] = verts[(vbase+u)*3+1];
        vz[u] = verts[(vbase+u)*3+2];
    }

    Top8 t0, t1;
    top8_init(t0); top8_init(t1);
#pragma unroll
    for (int q = 0; q < 8; ++q) {
        float sx = pc[q], sy = pc[M+q], sz = pc[2*M+q];
        {
            float dx=__fsub_rn(sx,vx[0]), dy=__fsub_rn(sy,vy[0]), dz=__fsub_rn(sz,vz[0]);
            float d = __fmaf_rn(dz,dz,__fmaf_rn(dy,dy,__fmul_rn(dx,dx)));
            unsigned cd = (unsigned)__builtin_amdgcn_readfirstlane(__float_as_uint(d));
            if (cd < t0.d7) ins8s(t0, cd, q);
        }
        {
            float dx=__fsub_rn(sx,vx[1]), dy=__fsub_rn(sy,vy[1]), dz=__fsub_rn(sz,vz[1]);
            float d = __fmaf_rn(dz,dz,__fmaf_rn(dy,dy,__fmul_rn(dx,dx)));
            unsigned cd = (unsigned)__builtin_amdgcn_readfirstlane(__float_as_uint(d));
            if (cd < t1.d7) ins8s(t1, cd, q);
        }
    }
    float T[2];
    T[0] = __uint_as_float(t0.d7);
    T[1] = __uint_as_float(t1.d7);

    // gate constants (PK): s = fma(px,c0, fma(py,c1, fma(pz,c2, pn)));
    // d2 = s + |v|^2 (+err<=~1e-4) -> gate s < T - (|v|^2 - MARGIN) is
    // strictly conservative. Rounding of c/v2m themselves is absorbed.
    float c0[2], c1[2], c2[2], v2m[2], Tg[2];
    if constexpr (PK) {
#pragma unroll
        for (int u = 0; u < 2; ++u) {
            c0[u] = __fmul_rn(-2.0f, vx[u]);
            c1[u] = __fmul_rn(-2.0f, vy[u]);
            c2[u] = __fmul_rn(-2.0f, vz[u]);
            float v2 = __fadd_rn(__fadd_rn(__fmul_rn(vx[u],vx[u]), __fmul_rn(vy[u],vy[u])),
                                 __fmul_rn(vz[u],vz[u]));
            v2m[u] = __fsub_rn(v2, MARGIN);
            Tg[u]  = __fsub_rn(T[u], v2m[u]);
        }
    }

    const float* __restrict__ px = pc;
    const float* __restrict__ py = pc + M;
    const float* __restrict__ pz = pc + 2*M;

    if constexpr (PK) {
        float4 cp[4];
#pragma unroll
        for (int j = 0; j < 4; ++j) cp[j] = pk[64*j + lane];

        for (int ob = 0; ob < M; ob += 256) {
            int nb = (ob + 256 < M) ? ob + 256 : 0;     // last prefetch dead
            float4 np[4];
#pragma unroll
            for (int j = 0; j < 4; ++j) np[j] = pk[nb + 64*j + lane];
            float s0[4], s1[4];
#pragma unroll
            for (int j = 0; j < 4; ++j) {
                s0[j] = __fmaf_rn(cp[j].x, c0[0], __fmaf_rn(cp[j].y, c1[0],
                        __fmaf_rn(cp[j].z, c2[0], cp[j].w)));
                s1[j] = __fmaf_rn(cp[j].x, c0[1], __fmaf_rn(cp[j].y, c1[1],
                        __fmaf_rn(cp[j].z, c2[1], cp[j].w)));
            }
            u64 g0[4], g1[4]; u64 any = 0;
#pragma unroll
            for (int j = 0; j < 4; ++j) {
                g0[j] = __ballot(s0[j] < Tg[0]);
                g1[j] = __ballot(s1[j] < Tg[1]);
                any |= g0[j] | g1[j];
            }
            if (any) {                               // wave-uniform rare path
#pragma unroll
                for (int j = 0; j < 4; ++j) {        // j ascending = idx ascending
                    if (g0[j]) {
                        float dx = __fsub_rn(cp[j].x, vx[0]);
                        float dy = __fsub_rn(cp[j].y, vy[0]);
                        float dz = __fsub_rn(cp[j].z, vz[0]);
                        float d2x = __fmaf_rn(dz,dz,__fmaf_rn(dy,dy,__fmul_rn(dx,dx)));
                        u64 em = __ballot(d2x < T[0]);   // exact, strict <
                        if (em) {
                            handle_s(em, d2x, ob + 64*j, t0, T[0]);
                            Tg[0] = __fsub_rn(T[0], v2m[0]);
                        }
                    }
                }
#pragma unroll
                for (int j = 0; j < 4; ++j) {
                    if (g1[j]) {
                        float dx = __fsub_rn(cp[j].x, vx[1]);
                        float dy = __fsub_rn(cp[j].y, vy[1]);
                        float dz = __fsub_rn(cp[j].z, vz[1]);
                        float d2x = __fmaf_rn(dz,dz,__fmaf_rn(dy,dy,__fmul_rn(dx,dx)));
                        u64 em = __ballot(d2x < T[1]);
                        if (em) {
                            handle_s(em, d2x, ob + 64*j, t1, T[1]);
                            Tg[1] = __fsub_rn(T[1], v2m[1]);
                        }
                    }
                }
            }
#pragma unroll
            for (int j = 0; j < 4; ++j) cp[j] = np[j];
        }
    } else {
        float cx[4], cy[4], cz[4];
#pragma unroll
        for (int j = 0; j < 4; ++j) {
            cx[j] = px[64*j + lane]; cy[j] = py[64*j + lane]; cz[j] = pz[64*j + lane];
        }
        for (int ob = 0; ob < M; ob += 256) {
            int nb = (ob + 256 < M) ? ob + 256 : 0;
            float nx[4], ny[4], nz[4];
#pragma unroll
            for (int j = 0; j < 4; ++j) {
                nx[j] = px[nb + 64*j + lane];
                ny[j] = py[nb + 64*j + lane];
                nz[j] = pz[nb + 64*j + lane];
            }
            float d[2][4];
#pragma unroll
            for (int u = 0; u < 2; ++u)
#pragma unroll
                for (int j = 0; j < 4; ++j) {
                    float dx = __fsub_rn(cx[j], vx[u]);
                    float dy = __fsub_rn(cy[j], vy[u]);
                    float dz = __fsub_rn(cz[j], vz[u]);
                    d[u][j] = __fmaf_rn(dz,dz,__fmaf_rn(dy,dy,__fmul_rn(dx,dx)));
                }
            u64 msk[2][4]; u64 any = 0;
#pragma unroll
            for (int u = 0; u < 2; ++u)
#pragma unroll
                for (int j = 0; j < 4; ++j) {
                    msk[u][j] = __ballot(d[u][j] < T[u]);
                    any |= msk[u][j];
                }
            if (any) {
#pragma unroll
                for (int j = 0; j < 4; ++j)
                    handle_s(msk[0][j], d[0][j], ob + 64*j, t0, T[0]);
#pragma unroll
                for (int j = 0; j < 4; ++j)
                    handle_s(msk[1][j], d[1][j], ob + 64*j, t1, T[1]);
            }
#pragma unroll
            for (int j = 0; j < 4; ++j) { cx[j]=nx[j]; cy[j]=ny[j]; cz[j]=nz[j]; }
        }
    }

    int m8[2][8];
    m8[0][0]=t0.i0; m8[0][1]=t0.i1; m8[0][2]=t0.i2; m8[0][3]=t0.i3;
    m8[0][4]=t0.i4; m8[0][5]=t0.i5; m8[0][6]=t0.i6; m8[0][7]=t0.i7;
    m8[1][0]=t1.i0; m8[1][1]=t1.i1; m8[1][2]=t1.i2; m8[1][3]=t1.i3;
    m8[1][4]=t1.i4; m8[1][5]=t1.i5; m8[1][6]=t1.i6; m8[1][7]=t1.i7;
#pragma unroll
    for (int u = 0; u < 2; ++u) {
        float w8[8];
#pragma unroll
        for (int k = 0; k < 8; ++k)
            w8[k] = wcalc<M>(pc, m8[u][k], vx[u], vy[u], vz[u]);
        const int n = vbase + u;
        for (int f = lane; f < DF; f += 64) {
            float e[8];
#pragma unroll
            for (int k = 0; k < 8; ++k) {
                float fv = TR ? featT[m8[u][k]*DF + f] : feat[f*M + m8[u][k]];
                e[k] = __fmul_rn(w8[k], fv);
            }
            float s = __fadd_rn(__fadd_rn(__fadd_rn(e[0],e[1]), __fadd_rn(e[2],e[3])),
                                __fadd_rn(__fadd_rn(e[4],e[5]), __fadd_rn(e[6],e[7])));
            out[n*OSTRIDE + COFF + f] = __fmul_rn(0.125f, s);
        }
    }
}

// LDS-tiled transpose (blocks 0..1535): feat [Df,M] -> featT [M,Df], both
// sides coalesced. Blocks 1536..1759: fill packed float4 (x,y,z,|p|^2)
// arrays (bit-copies of pc values -> scan numerics unchanged).
__global__ __launch_bounds__(256)
void tr_kernel(const float* __restrict__ f1, const float* __restrict__ f2,
               const float* __restrict__ f3,
               const float* __restrict__ pc1, const float* __restrict__ pc2,
               const float* __restrict__ pc3, float* __restrict__ ws)
{
    int b = blockIdx.x;
    if (b >= 1536) {                                // pack fill (PK tier only)
        int g = (b - 1536)*256 + threadIdx.x;       // 0..57343
        float x, y, z; float4* dst;
        if (g < 32768)      { x=pc1[g];      y=pc1[32768+g];  z=pc1[65536+g];  dst=(float4*)(ws+PK1OFF)+g; }
        else if (g < 49152) { int m=g-32768; x=pc2[m]; y=pc2[16384+m]; z=pc2[32768+m]; dst=(float4*)(ws+PK2OFF)+m; }
        else                { int m=g-49152; x=pc3[m]; y=pc3[8192+m];  z=pc3[16384+m]; dst=(float4*)(ws+PK3OFF)+m; }
        float pn = __fmaf_rn(z,z,__fmaf_rn(y,y,__fmul_rn(x,x)));
        *dst = make_float4(x, y, z, pn);
        return;
    }
    __shared__ float s[64][65];
    const float* src; float* dst; int M, DF, tm, tf;
    if (b < 512)       { src = f1; dst = ws;           M = 32768; DF = 64;  tm = b & 511;        tf = b >> 9; }
    else if (b < 1024) { src = f2; dst = ws + 2097152; M = 16384; DF = 128; tm = (b-512) & 255;  tf = (b-512) >> 8; }
    else               { src = f3; dst = ws + 4194304; M = 8192;  DF = 256; tm = (b-1024) & 127; tf = (b-1024) >> 7; }
    const int mb = tm*64, fb = tf*64;
    const int tid = threadIdx.x;
    const int a0 = tid & 63, a1 = tid >> 6;
#pragma unroll
    for (int i = 0; i < 16; ++i) {
        int ff = a1 + i*4;
        s[ff][a0] = src[(fb+ff)*M + mb + a0];
    }
    __syncthreads();
#pragma unroll
    for (int i = 0; i < 16; ++i) {
        int mm2 = a1 + i*4;
        dst[(mb+mm2)*DF + fb + a0] = s[a0][mm2];
    }
}

// Grid (R13/R15 winner, unchanged): 1537 blocks x 4 waves, U=2 verts/wave,
// one stage per block: b<512 s1, b<1024 s2, b<1536 s3, b=1536 coord-copy.
// 6144 scan waves = one residency round at 6 blocks/CU.
template<bool TR, bool PK>
__global__ __launch_bounds__(NT, 6)
void gp_kernel(const float* __restrict__ verts,
               const float* __restrict__ pc1, const float* __restrict__ f1,
               const float* __restrict__ pc2, const float* __restrict__ f2,
               const float* __restrict__ pc3, const float* __restrict__ f3,
               const float* __restrict__ ws,
               float* __restrict__ out)
{
    int b = blockIdx.x;
    if (b < 1536) {
        const int lane = threadIdx.x & 63;
        const int wv   = threadIdx.x >> 6;
        if (b < 512) {
            stage2v<32768,  64,   3, TR, PK>(verts, pc1, f1, ws,
                (const float4*)(ws+PK1OFF), out, (b*4 + wv)*2, lane);
        } else if (b < 1024) {
            stage2v<16384, 128,  67, TR, PK>(verts, pc2, f2, ws + 2097152,
                (const float4*)(ws+PK2OFF), out, ((b-512)*4 + wv)*2, lane);
        } else {
            stage2v< 8192, 256, 195, TR, PK>(verts, pc3, f3, ws + 4194304,
                (const float4*)(ws+PK3OFF), out, ((b-1024)*4 + wv)*2, lane);
        }
    } else {
        for (int i = threadIdx.x; i < NV*3; i += NT)
            out[(i/3)*OSTRIDE + (i % 3)] = verts[i];
    }
}

extern "C" void kernel_launch(void* const* d_in, const int* in_sizes, int n_in,
                              void* d_out, int out_size, void* d_ws, size_t ws_size,
                              hipStream_t stream) {
    const float* verts = (const float*)d_in[0];
    // d_in[1] = pc0_coords: unused (reference discards stage 0)
    const float* pc1 = (const float*)d_in[2];
    const float* f1  = (const float*)d_in[3];
    const float* pc2 = (const float*)d_in[4];
    const float* f2  = (const float*)d_in[5];
    const float* pc3 = (const float*)d_in[6];
    const float* f3  = (const float*)d_in[7];
    float* out = (float*)d_out;
    float* ws  = (float*)d_ws;

    const size_t need_tr = 6291456ull * 4ull;
    const size_t need_pk = (6291456ull + 229376ull) * 4ull;
    if (ws_size >= need_pk) {
        tr_kernel<<<1760, 256, 0, stream>>>(f1, f2, f3, pc1, pc2, pc3, ws);
        gp_kernel<true, true><<<1537, NT, 0, stream>>>(verts, pc1, f1, pc2, f2, pc3, f3, ws, out);
    } else if (ws_size >= need_tr) {
        tr_kernel<<<1536, 256, 0, stream>>>(f1, f2, f3, pc1, pc2, pc3, ws);
        gp_kernel<true, false><<<1537, NT, 0, stream>>>(verts, pc1, f1, pc2, f2, pc3, f3, ws, out);
    } else {
        gp_kernel<false, false><<<1537, NT, 0, stream>>>(verts, pc1, f1, pc2, f2, pc3, f3, ws, out);
    }
}